// Round 3
// baseline (458.307 us; speedup 1.0000x reference)
//
#include <hip/hip_runtime.h>

// GroupLasso collapses to: out = 0.12f * (sum(w*w) + sum(b*b))
//   ROOT_GAMMA + COARSE_GAMMA + FINE_GAMMA = 0.02 + 0.04 + 0.06 = 0.12
// (segment_sum summed over all segments == total sum; coarse_map is irrelevant)
//
// Single fused kernel: grid-stride float4 sum-of-squares with 4 independent
// accumulator/load streams, block shuffle-reduce, last-block-done final
// reduction (agent-scope atomics handle cross-XCD visibility). The ticket
// counter lives in d_ws and is zeroed by a graph-legal hipMemsetAsync node.
//
// NOTE: resubmission of round-2 kernel verbatim — round 2 hit
// GPUAcquisitionTimeout (no bench data), so no evidence-driven change is
// justified yet.

constexpr int BLOCK = 256;
constexpr int GRID  = 2048;

__global__ __launch_bounds__(BLOCK) void grouplasso_fused(
    const float4* __restrict__ w4, long long nw4,
    const float4* __restrict__ b4, long long nb4,
    float* partials, unsigned int* counter, float* out)
{
    const long long stride = (long long)GRID * BLOCK;
    const long long tid    = (long long)blockIdx.x * BLOCK + threadIdx.x;

    float a0 = 0.f, a1 = 0.f, a2 = 0.f, a3 = 0.f;

    // weights: 4-way unrolled grid-stride, 4 independent load streams
    long long i = tid;
    for (; i + 3 * stride < nw4; i += 4 * stride) {
        float4 v0 = w4[i];
        float4 v1 = w4[i + stride];
        float4 v2 = w4[i + 2 * stride];
        float4 v3 = w4[i + 3 * stride];
        a0 = fmaf(v0.x, v0.x, a0); a0 = fmaf(v0.y, v0.y, a0);
        a0 = fmaf(v0.z, v0.z, a0); a0 = fmaf(v0.w, v0.w, a0);
        a1 = fmaf(v1.x, v1.x, a1); a1 = fmaf(v1.y, v1.y, a1);
        a1 = fmaf(v1.z, v1.z, a1); a1 = fmaf(v1.w, v1.w, a1);
        a2 = fmaf(v2.x, v2.x, a2); a2 = fmaf(v2.y, v2.y, a2);
        a2 = fmaf(v2.z, v2.z, a2); a2 = fmaf(v2.w, v2.w, a2);
        a3 = fmaf(v3.x, v3.x, a3); a3 = fmaf(v3.y, v3.y, a3);
        a3 = fmaf(v3.z, v3.z, a3); a3 = fmaf(v3.w, v3.w, a3);
    }
    for (; i < nw4; i += stride) {
        float4 v = w4[i];
        a0 = fmaf(v.x, v.x, a0); a0 = fmaf(v.y, v.y, a0);
        a0 = fmaf(v.z, v.z, a0); a0 = fmaf(v.w, v.w, a0);
    }
    // bias (small)
    for (long long j = tid; j < nb4; j += stride) {
        float4 v = b4[j];
        a1 = fmaf(v.x, v.x, a1); a1 = fmaf(v.y, v.y, a1);
        a1 = fmaf(v.z, v.z, a1); a1 = fmaf(v.w, v.w, a1);
    }

    float acc = (a0 + a1) + (a2 + a3);

    // block reduce: wave64 shuffle + LDS across 4 waves
    __shared__ float smem[BLOCK / 64];
    __shared__ int is_last;
    #pragma unroll
    for (int off = 32; off > 0; off >>= 1)
        acc += __shfl_down(acc, off, 64);
    const int lane = threadIdx.x & 63;
    const int wave = threadIdx.x >> 6;
    if (lane == 0) smem[wave] = acc;
    __syncthreads();

    if (threadIdx.x == 0) {
        float s = smem[0] + smem[1] + smem[2] + smem[3];
        __hip_atomic_store(&partials[blockIdx.x], s,
                           __ATOMIC_RELEASE, __HIP_MEMORY_SCOPE_AGENT);
        unsigned prev = __hip_atomic_fetch_add(counter, 1u,
                           __ATOMIC_ACQ_REL, __HIP_MEMORY_SCOPE_AGENT);
        is_last = (prev == (unsigned)(GRID - 1));
    }
    __syncthreads();   // also orders smem reuse below

    if (is_last) {
        // final reduction over GRID partials by the whole last block
        float f = 0.f;
        for (int t = threadIdx.x; t < GRID; t += BLOCK)
            f += __hip_atomic_load(&partials[t],
                                   __ATOMIC_ACQUIRE, __HIP_MEMORY_SCOPE_AGENT);
        #pragma unroll
        for (int off = 32; off > 0; off >>= 1)
            f += __shfl_down(f, off, 64);
        if (lane == 0) smem[wave] = f;
        __syncthreads();
        if (threadIdx.x == 0)
            out[0] = 0.12f * (smem[0] + smem[1] + smem[2] + smem[3]);
    }
}

extern "C" void kernel_launch(void* const* d_in, const int* in_sizes, int n_in,
                              void* d_out, int out_size, void* d_ws, size_t ws_size,
                              hipStream_t stream) {
    const float* w = (const float*)d_in[0];   // fc_weights, NUM_FINE*FEAT_DIM fp32
    const float* b = (const float*)d_in[1];   // fc_bias, NUM_FINE fp32
    // d_in[2] (coarse_map) is mathematically irrelevant — see header comment.

    const long long nw4 = (long long)in_sizes[0] >> 2;   // 51.2e6 % 4 == 0
    const long long nb4 = (long long)in_sizes[1] >> 2;   // 1e5  % 4 == 0

    unsigned int* counter = (unsigned int*)d_ws;               // 4 B, poisoned
    float* partials = (float*)((char*)d_ws + 256);             // GRID floats
    float* out = (float*)d_out;

    hipMemsetAsync(counter, 0, sizeof(unsigned int), stream);  // graph-legal memset node
    grouplasso_fused<<<GRID, BLOCK, 0, stream>>>(
        (const float4*)w, nw4, (const float4*)b, nb4, partials, counter, out);
}

// Round 4
// 287.122 us; speedup vs baseline: 1.5962x; 1.5962x over previous
//
#include <hip/hip_runtime.h>

// GroupLasso collapses to: out = 0.12f * (sum(w*w) + sum(b*b))
//   ROOT_GAMMA + COARSE_GAMMA + FINE_GAMMA = 0.02 + 0.04 + 0.06 = 0.12
// (segment_sum summed over all segments == total sum; coarse_map is irrelevant)
//
// R3 post-mortem: agent-scope release/acquire atomics forced per-block L2
// writeback+invalidate (gfx950 per-XCD L2 non-coherent) -> 262 us @ 4.9% HBM.
// R4: plain device-scope hardware fp32 atomicAdd per block (no fences needed
// — the RMW is the only communication), d_out zeroed by a graph-legal
// hipMemsetAsync node. Simple round-1 load loop (known good).

constexpr int BLOCK = 256;
constexpr int GRID  = 2048;

__global__ __launch_bounds__(BLOCK) void grouplasso_sumsq(
    const float4* __restrict__ w4, long long nw4,
    const float4* __restrict__ b4, long long nb4,
    float* __restrict__ out)
{
    const long long stride = (long long)GRID * BLOCK;
    const long long tid    = (long long)blockIdx.x * BLOCK + threadIdx.x;

    float acc = 0.f;

    // weights: simple grid-stride float4 (coalesced 16 B/lane)
    for (long long i = tid; i < nw4; i += stride) {
        float4 v = w4[i];
        acc = fmaf(v.x, v.x, acc);
        acc = fmaf(v.y, v.y, acc);
        acc = fmaf(v.z, v.z, acc);
        acc = fmaf(v.w, v.w, acc);
    }
    // bias (small)
    for (long long j = tid; j < nb4; j += stride) {
        float4 v = b4[j];
        acc = fmaf(v.x, v.x, acc);
        acc = fmaf(v.y, v.y, acc);
        acc = fmaf(v.z, v.z, acc);
        acc = fmaf(v.w, v.w, acc);
    }

    // block reduce: wave64 shuffle + LDS across 4 waves
    #pragma unroll
    for (int off = 32; off > 0; off >>= 1)
        acc += __shfl_down(acc, off, 64);
    __shared__ float smem[BLOCK / 64];
    const int lane = threadIdx.x & 63;
    const int wave = threadIdx.x >> 6;
    if (lane == 0) smem[wave] = acc;
    __syncthreads();

    if (threadIdx.x == 0) {
        float s = smem[0] + smem[1] + smem[2] + smem[3];
        atomicAdd(out, 0.12f * s);   // device-scope HW fp32 atomic, no fences
    }
}

extern "C" void kernel_launch(void* const* d_in, const int* in_sizes, int n_in,
                              void* d_out, int out_size, void* d_ws, size_t ws_size,
                              hipStream_t stream) {
    const float* w = (const float*)d_in[0];   // fc_weights, NUM_FINE*FEAT_DIM fp32
    const float* b = (const float*)d_in[1];   // fc_bias, NUM_FINE fp32
    // d_in[2] (coarse_map) is mathematically irrelevant — see header comment.

    const long long nw4 = (long long)in_sizes[0] >> 2;   // 51.2e6 % 4 == 0
    const long long nb4 = (long long)in_sizes[1] >> 2;   // 1e5  % 4 == 0

    float* out = (float*)d_out;

    // d_out is re-poisoned to 0xAA before every timed launch — zero it with a
    // graph-legal async memset node, then accumulate into it atomically.
    hipMemsetAsync(out, 0, sizeof(float), stream);
    grouplasso_sumsq<<<GRID, BLOCK, 0, stream>>>(
        (const float4*)w, nw4, (const float4*)b, nb4, out);
}